// Round 14
// baseline (158.625 us; speedup 1.0000x reference)
//
#include <hip/hip_runtime.h>

#define E_EDGES 160000
#define N_NODES 10000
#define SLOTS   32      // per-node bucket capacity; overflow falls back to atomics

// 24^(-0.5)
#define TEMP 0.20412414523193154f

typedef __fp16 half2_t __attribute__((ext_vector_type(2)));
typedef __fp16 half8_t __attribute__((ext_vector_type(8)));
typedef float f32x4 __attribute__((ext_vector_type(4)));

__device__ __forceinline__ float fdot2(half2_t a, half2_t b, float c) {
#if __has_builtin(__builtin_amdgcn_fdot2)
    return __builtin_amdgcn_fdot2(a, b, c, false);
#else
    return fmaf((float)a.x, (float)b.x, fmaf((float)a.y, (float)b.y, c));
#endif
}
__device__ __forceinline__ half2_t pk(float a, float b) {
    return __builtin_amdgcn_cvt_pkrtz(a, b);
}

// prep: W2 [768][64] f32 -> f16 A-frag order; W1 [64][32] -> f16 A-frag order
// with row permutation so Phase-A MFMA output lands in conv B-frag order;
// zero cnt + num/den.
__global__ __launch_bounds__(256)
void prep_kernel(const float* __restrict__ W2, const float* __restrict__ W1,
                 unsigned* __restrict__ w2p, uint4* __restrict__ w1pk,
                 int* __restrict__ cnt, float4* __restrict__ zbuf)
{
    int u = blockIdx.x * blockDim.x + threadIdx.x;   // u < 24576
    if (u < N_NODES) cnt[u] = 0;
    // zero num (N*24) + den (N*4) = 70000 float4 (contiguous)
    #pragma unroll
    for (int i = 0; i < 3; ++i) {
        int z = u + i * 24576;
        if (z < (N_NODES * 28) / 4) zbuf[z] = make_float4(0.f, 0.f, 0.f, 0.f);
    }
    // W1 pack: tile t (0..3), lane l: A-frag row r16=l&15, k-chunk q=l>>4.
    if (u < 256) {
        int t = u >> 6, l = u & 63;
        int r16 = l & 15, q = l >> 4;
        int row = 32*(t >> 1) + ((r16 >> 2) << 3) + ((t & 1) << 2) + (r16 & 3);
        union { __fp16 h[8]; uint4 v; } o2;
        #pragma unroll
        for (int i = 0; i < 8; ++i) o2.h[i] = (__fp16)W1[row*32 + q*8 + i];
        w1pk[(t << 6) + l] = o2.v;
    }
    int tp    = u & 3;
    int lane  = (u >> 2) & 63;
    int piece = (u >> 8) & 3;
    int c     = u >> 10;
    int em = lane & 15, quad = lane >> 4;
    int row = 32*c + ((piece >> 1) << 4) + em;
    int col = ((piece & 1) << 5) + quad*8 + 2*tp;
    union { half2_t h; unsigned v; } o;
    o.h.x = (__fp16)W2[row*64 + col];
    o.h.y = (__fp16)W2[row*64 + col + 1];
    w2p[u] = o.v;
}

// 4-MFMA quartet + dot tail: produces the 3 conv components (replicated in
// all lanes after the shfl reduce) for one c-row.
#define MFMA4_TAIL(F0,F1,F2,F3,HL,HH,BB0,BB1,T2,P0,P1,P2) { \
    f32x4 a0 = {(BB0).x, (BB0).y, (BB0).z, (BB0).w}; \
    a0 = __builtin_amdgcn_mfma_f32_16x16x32_f16((F0), (HL), a0, 0, 0, 0); \
    a0 = __builtin_amdgcn_mfma_f32_16x16x32_f16((F1), (HH), a0, 0, 0, 0); \
    f32x4 a1 = {(BB1).x, (BB1).y, (BB1).z, (BB1).w}; \
    a1 = __builtin_amdgcn_mfma_f32_16x16x32_f16((F2), (HL), a1, 0, 0, 0); \
    a1 = __builtin_amdgcn_mfma_f32_16x16x32_f16((F3), (HH), a1, 0, 0, 0); \
    P0 = 0.f; P1 = 0.f; P2 = 0.f; \
    _Pragma("unroll") \
    for (int r = 0; r < 4; ++r) { \
        half2_t rp = pk(a0[r], a1[r]); \
        P0 = fdot2(rp, (T2)[r][0], P0); \
        P1 = fdot2(rp, (T2)[r][1], P1); \
        P2 = fdot2(rp, (T2)[r][2], P2); \
    } \
    P0 += __shfl_xor(P0, 16); P0 += __shfl_xor(P0, 32); \
    P1 += __shfl_xor(P1, 16); P1 += __shfl_xor(P1, 32); \
    P2 += __shfl_xor(P2, 16); P2 += __shfl_xor(P2, 32); \
}

// ---- fused per-edge kernel v4: R9 structure (1 edge/thread, 256-thr blocks,
// grid 2500, 10000 waves) with k+q co-staged in 64 KB LDS. The kq pass fuses
// k-row cg with q-row 8+cg -> kreg never exists; barriers 5 -> 3 per 64 edges.
// (R13 established R9's residency is ~2 blocks/CU, so 67 KB LDS is
// occupancy-free; R13's regression was its 2-edges/thread serialization.)
__global__ __launch_bounds__(256, 3)
void fused_kernel(const int* __restrict__ src, const int* __restrict__ dst,
                  const float* __restrict__ basis, const float* __restrict__ efeat,
                  const float* __restrict__ f,
                  const uint4* __restrict__ w1pk, const float* __restrict__ b1,
                  const uint4* __restrict__ w2p, const float* __restrict__ b2,
                  unsigned char* __restrict__ bkt, int* __restrict__ cnt,
                  float* __restrict__ num, float* __restrict__ den)
{
    __shared__ __fp16 w2s[2*16384];     // 64 KB: [0]=k (later v), [16384]=q
    __shared__ float  b2s[768];         // 3 KB

    const int tid  = threadIdx.x;
    const int lane = tid & 63;
    const int wid  = tid >> 6;
    const int em   = lane & 15;
    const int quad = lane >> 4;
    const int e = (blockIdx.x * 4 + wid) * 16 + em;

    // ---- stage k-group + q-group (16 uint4/thread, contiguous) + b2 ----
    {
        uint4* d4 = (uint4*)w2s;
        #pragma unroll
        for (int i = 0; i < 16; ++i) d4[i*256 + tid] = w2p[i*256 + tid];
        if (tid < 192) ((float4*)b2s)[tid] = ((const float4*)b2)[tid];
    }

    // ---- bucket placement: one atomic per edge, slot broadcast to all quads ----
    int p_slot = 0, dn0 = 0;
    if (quad == 0) {
        dn0 = dst[e];
        p_slot = atomicAdd(&cnt[dn0], 1);
    }
    const int pb  = __shfl(p_slot, em);
    const int dnb = __shfl(dn0, em);

    // ---- W1 A-fragments + bias (tiny, L2-resident) ----
    half8_t w1f[4];
    #pragma unroll
    for (int t = 0; t < 4; ++t) {
        union { uint4 u; half8_t v; } c;
        c.u = w1pk[(t << 6) + lane];
        w1f[t] = c.v;
    }
    float4 b1a = *(const float4*)(b1 + quad*8);
    float4 b1b = *(const float4*)(b1 + quad*8 + 4);
    float4 b1c = *(const float4*)(b1 + 32 + quad*8);
    float4 b1d = *(const float4*)(b1 + 32 + quad*8 + 4);

    // ---- x B-fragment: this quad's 8 features of edge e ----
    half8_t xb;
    {
        const float4* xv = (const float4*)(efeat + (size_t)e * 32 + quad*8);
        float4 x0 = xv[0], x1 = xv[1];
        union { half2_t h2[4]; half8_t v; } xu;
        xu.h2[0] = pk(x0.x, x0.y); xu.h2[1] = pk(x0.z, x0.w);
        xu.h2[2] = pk(x1.x, x1.y); xu.h2[3] = pk(x1.z, x1.w);
        xb = xu.v;
    }

    // ---- Phase A via MFMA: h = relu(W1 @ x + b1), C-init = bias ----
    half8_t h_lo, h_hi;
    {
        f32x4 ha0 = {b1a.x, b1a.y, b1a.z, b1a.w};
        f32x4 ha1 = {b1b.x, b1b.y, b1b.z, b1b.w};
        f32x4 ha2 = {b1c.x, b1c.y, b1c.z, b1c.w};
        f32x4 ha3 = {b1d.x, b1d.y, b1d.z, b1d.w};
        ha0 = __builtin_amdgcn_mfma_f32_16x16x32_f16(w1f[0], xb, ha0, 0, 0, 0);
        ha1 = __builtin_amdgcn_mfma_f32_16x16x32_f16(w1f[1], xb, ha1, 0, 0, 0);
        ha2 = __builtin_amdgcn_mfma_f32_16x16x32_f16(w1f[2], xb, ha2, 0, 0, 0);
        ha3 = __builtin_amdgcn_mfma_f32_16x16x32_f16(w1f[3], xb, ha3, 0, 0, 0);
        union { half2_t h2[4]; half8_t v; } lo, hi;
        lo.h2[0] = pk(fmaxf(ha0[0],0.f), fmaxf(ha0[1],0.f));
        lo.h2[1] = pk(fmaxf(ha0[2],0.f), fmaxf(ha0[3],0.f));
        lo.h2[2] = pk(fmaxf(ha1[0],0.f), fmaxf(ha1[1],0.f));
        lo.h2[3] = pk(fmaxf(ha1[2],0.f), fmaxf(ha1[3],0.f));
        hi.h2[0] = pk(fmaxf(ha2[0],0.f), fmaxf(ha2[1],0.f));
        hi.h2[1] = pk(fmaxf(ha2[2],0.f), fmaxf(ha2[3],0.f));
        hi.h2[2] = pk(fmaxf(ha3[0],0.f), fmaxf(ha3[1],0.f));
        hi.h2[3] = pk(fmaxf(ha3[2],0.f), fmaxf(ha3[3],0.f));
        h_lo = lo.v; h_hi = hi.v;
    }

    // ---- Phase B: tmp2 quarter (mp = quad*4..+4), pairs (m', m'+16) ----
    half2_t t2[4][3];
    {
        float bas[18];
        const float2* bv = (const float2*)(basis + (size_t)e * 18);
        #pragma unroll
        for (int i = 0; i < 9; ++i) { float2 t = bv[i]; bas[2*i] = t.x; bas[2*i+1] = t.y; }
        const float* fp = f + (size_t)src[e] * 48 + quad*6;
        float fl[6], fh[6];
        #pragma unroll
        for (int i = 0; i < 3; ++i) {
            float2 a = *(const float2*)(fp + 2*i);      fl[2*i] = a.x; fl[2*i+1] = a.y;
            float2 b = *(const float2*)(fp + 24 + 2*i); fh[2*i] = b.x; fh[2*i+1] = b.y;
        }
        #pragma unroll
        for (int jj = 0; jj < 4; ++jj) {
            const int mr = (jj >> 1) * 3;
            const int rb = (jj & 1) * 3;
            #pragma unroll
            for (int d = 0; d < 3; ++d) {
                float lo = fmaf(fl[mr+0], bas[rb+d],
                           fmaf(fl[mr+1], bas[6+rb+d], fl[mr+2] * bas[12+rb+d]));
                float hi = fmaf(fh[mr+0], bas[rb+d],
                           fmaf(fh[mr+1], bas[6+rb+d], fh[mr+2] * bas[12+rb+d]));
                t2[jj][d] = pk(lo, hi);
            }
        }
    }

    __syncthreads();   // barrier 1: k+q staged

    // ---- fused kq pass: per cg, k row cg and q row 8+cg; no kreg ----
    float sreg[4];
    #pragma unroll
    for (int cg = 0; cg < 8; ++cg) {
        const __fp16* kp = w2s + ((cg*4)*64 + lane)*8;
        half8_t kf0 = *(const half8_t*)(kp);
        half8_t kf1 = *(const half8_t*)(kp + 512);
        half8_t kf2 = *(const half8_t*)(kp + 1024);
        half8_t kf3 = *(const half8_t*)(kp + 1536);
        const __fp16* qp = kp + 16384;
        half8_t qf0 = *(const half8_t*)(qp);
        half8_t qf1 = *(const half8_t*)(qp + 512);
        half8_t qf2 = *(const half8_t*)(qp + 1024);
        half8_t qf3 = *(const half8_t*)(qp + 1536);
        float4 bk0 = *(const float4*)(b2s + 32*cg + quad*4);
        float4 bk1 = *(const float4*)(b2s + 32*cg + 16 + quad*4);
        float4 bq0 = *(const float4*)(b2s + 32*(8+cg) + quad*4);
        float4 bq1 = *(const float4*)(b2s + 32*(8+cg) + 16 + quad*4);
        float k0, k1, k2, q0, q1, q2;
        MFMA4_TAIL(kf0,kf1,kf2,kf3, h_lo,h_hi, bk0,bk1, t2, k0,k1,k2);
        MFMA4_TAIL(qf0,qf1,qf2,qf3, h_lo,h_hi, bq0,bq1, t2, q0,q1,q2);
        float s_ = q0*k0 + q1*k1 + q2*k2;
        if ((cg & 1) == 0) sreg[cg>>1] = s_; else sreg[cg>>1] += s_;
    }

    // exp(leaky_relu(s*temp)); no max subtraction (verified R2-R13)
    float exv[4];
    #pragma unroll
    for (int hh = 0; hh < 4; ++hh) {
        float s = sreg[hh] * TEMP;
        s = (s > 0.0f) ? s : 0.2f * s;
        exv[hh] = __expf(s);
    }

    __syncthreads();   // barrier 2: all reads of k region done

    // ---- stage v-group into the k region (8 uint4/thread) ----
    {
        uint4* d4 = (uint4*)w2s;
        #pragma unroll
        for (int i = 0; i < 8; ++i) d4[i*256 + tid] = w2p[4096 + i*256 + tid];
    }

    __syncthreads();   // barrier 3: v staged

    // ---- v pass (c = 16..23) ----
    float vreg[8][3];
    #pragma unroll
    for (int cg = 0; cg < 8; ++cg) {
        const __fp16* vp = w2s + ((cg*4)*64 + lane)*8;
        half8_t vf0 = *(const half8_t*)(vp);
        half8_t vf1 = *(const half8_t*)(vp + 512);
        half8_t vf2 = *(const half8_t*)(vp + 1024);
        half8_t vf3 = *(const half8_t*)(vp + 1536);
        float4 bv0 = *(const float4*)(b2s + 32*(16+cg) + quad*4);
        float4 bv1 = *(const float4*)(b2s + 32*(16+cg) + 16 + quad*4);
        MFMA4_TAIL(vf0,vf1,vf2,vf3, h_lo,h_hi, bv0,bv1, t2,
                   vreg[cg][0], vreg[cg][1], vreg[cg][2]);
    }

    // ---- epilogue: 64 B bucket record, four plain 16 B stores ----
    if (pb < SLOTS) {
        unsigned char* rec = bkt + ((size_t)dnb * SLOTS + pb) * 64;
        if (quad == 3) {
            *(float4*)(rec + 48) = make_float4(exv[0], exv[1], exv[2], exv[3]);
        } else {
            union { half2_t h2[4]; uint4 u; } pv;
            if (quad == 0) {
                pv.h2[0] = pk(vreg[0][0], vreg[0][1]);
                pv.h2[1] = pk(vreg[0][2], vreg[1][0]);
                pv.h2[2] = pk(vreg[1][1], vreg[1][2]);
                pv.h2[3] = pk(vreg[2][0], vreg[2][1]);
            } else if (quad == 1) {
                pv.h2[0] = pk(vreg[2][2], vreg[3][0]);
                pv.h2[1] = pk(vreg[3][1], vreg[3][2]);
                pv.h2[2] = pk(vreg[4][0], vreg[4][1]);
                pv.h2[3] = pk(vreg[4][2], vreg[5][0]);
            } else {
                pv.h2[0] = pk(vreg[5][1], vreg[5][2]);
                pv.h2[1] = pk(vreg[6][0], vreg[6][1]);
                pv.h2[2] = pk(vreg[6][2], vreg[7][0]);
                pv.h2[3] = pk(vreg[7][1], vreg[7][2]);
            }
            *(uint4*)(rec + quad*16) = pv.u;
        }
    } else {
        // rare overflow: atomic fallback
        float* nb = num + (size_t)dnb * 24;
        if (quad == 0) {
            atomicAdd(nb+0, exv[0]*vreg[0][0]); atomicAdd(nb+1, exv[0]*vreg[0][1]);
            atomicAdd(nb+2, exv[0]*vreg[0][2]); atomicAdd(nb+3, exv[0]*vreg[1][0]);
            atomicAdd(nb+4, exv[0]*vreg[1][1]); atomicAdd(nb+5, exv[0]*vreg[1][2]);
            atomicAdd(nb+6, exv[1]*vreg[2][0]); atomicAdd(nb+7, exv[1]*vreg[2][1]);
        } else if (quad == 1) {
            atomicAdd(nb+8,  exv[1]*vreg[2][2]); atomicAdd(nb+9,  exv[1]*vreg[3][0]);
            atomicAdd(nb+10, exv[1]*vreg[3][1]); atomicAdd(nb+11, exv[1]*vreg[3][2]);
            atomicAdd(nb+12, exv[2]*vreg[4][0]); atomicAdd(nb+13, exv[2]*vreg[4][1]);
            atomicAdd(nb+14, exv[2]*vreg[4][2]); atomicAdd(nb+15, exv[2]*vreg[5][0]);
        } else if (quad == 2) {
            atomicAdd(nb+16, exv[2]*vreg[5][1]); atomicAdd(nb+17, exv[2]*vreg[5][2]);
            atomicAdd(nb+18, exv[3]*vreg[6][0]); atomicAdd(nb+19, exv[3]*vreg[6][1]);
            atomicAdd(nb+20, exv[3]*vreg[6][2]); atomicAdd(nb+21, exv[3]*vreg[7][0]);
            atomicAdd(nb+22, exv[3]*vreg[7][1]); atomicAdd(nb+23, exv[3]*vreg[7][2]);
        } else {
            float* db = den + (size_t)dnb * 4;
            atomicAdd(db+0, exv[0]); atomicAdd(db+1, exv[1]);
            atomicAdd(db+2, exv[2]); atomicAdd(db+3, exv[3]);
        }
    }
}

// ---- gather: R9-proven v1. One wave per node; contiguous 64 B records ----
__global__ __launch_bounds__(256)
void gather_kernel(const int* __restrict__ cnt, const unsigned char* __restrict__ bkt,
                   const float* __restrict__ num, const float* __restrict__ den,
                   float* __restrict__ out)
{
    const int lane = threadIdx.x & 63;
    const int wid  = threadIdx.x >> 6;
    const int n = blockIdx.x * 4 + wid;
    if (n >= N_NODES) return;
    int deg = cnt[n];
    if (deg > SLOTS) deg = SLOTS;
    const unsigned char* rec = bkt + (size_t)n * SLOTS * 64;

    const int j = lane & 31;            // output component (j < 24)
    const int half = lane >> 5;         // slot-range split
    const int hd = (j < 24) ? (j / 6) : 0;

    float acc = 0.f, dn_ = 0.f;
    if (j < 24 && half == 0) {          // merge rare overflow contributions
        acc = num[n*24 + j];
        dn_ = den[n*4 + hd];
    }
    if (j < 24) {
        #pragma unroll 2
        for (int i = half; i < deg; i += 2) {
            const unsigned char* r = rec + (size_t)i * 64;
            float ex = *(const float*)(r + 48 + hd*4);
            float v  = (float)*(const __fp16*)(r + j*2);
            dn_ += ex;
            acc = fmaf(ex, v, acc);
        }
    }
    acc += __shfl_xor(acc, 32);
    dn_ += __shfl_xor(dn_, 32);
    if (half == 0 && j < 24) {
        out[n*24 + j] = (dn_ > 0.f) ? (acc / dn_) : 0.f;
    }
}

extern "C" void kernel_launch(void* const* d_in, const int* in_sizes, int n_in,
                              void* d_out, int out_size, void* d_ws, size_t ws_size,
                              hipStream_t stream)
{
    const int*   src   = (const int*)d_in[0];
    const int*   dst   = (const int*)d_in[1];
    const float* basis = (const float*)d_in[2];
    const float* ef    = (const float*)d_in[3];
    const float* f     = (const float*)d_in[4];
    const float* W1    = (const float*)d_in[5];
    const float* b1    = (const float*)d_in[6];
    const float* W2    = (const float*)d_in[7];
    const float* b2    = (const float*)d_in[8];
    float* out = (float*)d_out;

    // workspace (~21.75 MB total; proven budget)
    unsigned char* bkt = (unsigned char*)d_ws;                      // N*SLOTS*64 B (20.48 MB)
    float* num = (float*)(bkt + (size_t)N_NODES * SLOTS * 64);      // N*24 f32 (0.96 MB)
    float* den = num + (size_t)N_NODES * 24;                        // N*4 f32 (0.16 MB)
    unsigned* w2p = (unsigned*)(den + (size_t)N_NODES * 4);         // 24576 u32 (96 KB)
    int* cnt = (int*)(w2p + 24576);                                 // N int (40 KB)
    uint4* w1pk = (uint4*)(cnt + N_NODES);                          // 256 uint4 (4 KB)

    prep_kernel<<<96, 256, 0, stream>>>(W2, W1, w2p, w1pk, cnt, (float4*)num);

    fused_kernel<<<E_EDGES / 64, 256, 0, stream>>>(src, dst, basis, ef, f,
                                                   w1pk, b1, (const uint4*)w2p, b2,
                                                   bkt, cnt, num, den);

    gather_kernel<<<(N_NODES + 3) / 4, 256, 0, stream>>>(cnt, bkt, num, den, out);
}

// Round 15
// 137.267 us; speedup vs baseline: 1.1556x; 1.1556x over previous
//
#include <hip/hip_runtime.h>

#define E_EDGES 160000
#define N_NODES 10000
#define SLOTS   32      // per-node bucket capacity; overflow falls back to atomics

// 24^(-0.5)
#define TEMP 0.20412414523193154f

typedef __fp16 half2_t __attribute__((ext_vector_type(2)));
typedef __fp16 half8_t __attribute__((ext_vector_type(8)));
typedef float f32x4 __attribute__((ext_vector_type(4)));

__device__ __forceinline__ float fdot2(half2_t a, half2_t b, float c) {
#if __has_builtin(__builtin_amdgcn_fdot2)
    return __builtin_amdgcn_fdot2(a, b, c, false);
#else
    return fmaf((float)a.x, (float)b.x, fmaf((float)a.y, (float)b.y, c));
#endif
}
__device__ __forceinline__ half2_t pk(float a, float b) {
    return __builtin_amdgcn_cvt_pkrtz(a, b);
}

// prep: W2 [768][64] f32 -> f16 A-frag order; W1 [64][32] -> f16 A-frag order
// with row permutation so Phase-A MFMA output lands in conv B-frag order;
// zero cnt + num/den.
__global__ __launch_bounds__(256)
void prep_kernel(const float* __restrict__ W2, const float* __restrict__ W1,
                 unsigned* __restrict__ w2p, uint4* __restrict__ w1pk,
                 int* __restrict__ cnt, float4* __restrict__ zbuf)
{
    int u = blockIdx.x * blockDim.x + threadIdx.x;   // u < 24576
    if (u < N_NODES) cnt[u] = 0;
    // zero num (N*24) + den (N*4) = 70000 float4 (contiguous)
    #pragma unroll
    for (int i = 0; i < 3; ++i) {
        int z = u + i * 24576;
        if (z < (N_NODES * 28) / 4) zbuf[z] = make_float4(0.f, 0.f, 0.f, 0.f);
    }
    // W1 pack: tile t (0..3), lane l: A-frag row r16=l&15, k-chunk q=l>>4.
    if (u < 256) {
        int t = u >> 6, l = u & 63;
        int r16 = l & 15, q = l >> 4;
        int row = 32*(t >> 1) + ((r16 >> 2) << 3) + ((t & 1) << 2) + (r16 & 3);
        union { __fp16 h[8]; uint4 v; } o2;
        #pragma unroll
        for (int i = 0; i < 8; ++i) o2.h[i] = (__fp16)W1[row*32 + q*8 + i];
        w1pk[(t << 6) + l] = o2.v;
    }
    int tp    = u & 3;
    int lane  = (u >> 2) & 63;
    int piece = (u >> 8) & 3;
    int c     = u >> 10;
    int em = lane & 15, quad = lane >> 4;
    int row = 32*c + ((piece >> 1) << 4) + em;
    int col = ((piece & 1) << 5) + quad*8 + 2*tp;
    union { half2_t h; unsigned v; } o;
    o.h.x = (__fp16)W2[row*64 + col];
    o.h.y = (__fp16)W2[row*64 + col + 1];
    w2p[u] = o.v;
}

#define CONV_GROUP(cbase, OUT) \
    _Pragma("unroll") \
    for (int cg = 0; cg < 8; ++cg) { \
        const int c = (cbase) + cg; \
        const __fp16* base = w2s + ((cg*4)*64 + lane)*8; \
        half8_t wa0 = *(const half8_t*)(base); \
        half8_t wa1 = *(const half8_t*)(base + 64*8); \
        half8_t wb0 = *(const half8_t*)(base + 2*64*8); \
        half8_t wb1 = *(const half8_t*)(base + 3*64*8); \
        float4 bb0 = *(const float4*)(b2s + 32*c + quad*4); \
        float4 bb1 = *(const float4*)(b2s + 32*c + 16 + quad*4); \
        f32x4 acc0 = {bb0.x, bb0.y, bb0.z, bb0.w}; \
        acc0 = __builtin_amdgcn_mfma_f32_16x16x32_f16(wa0, h_lo, acc0, 0, 0, 0); \
        acc0 = __builtin_amdgcn_mfma_f32_16x16x32_f16(wa1, h_hi, acc0, 0, 0, 0); \
        f32x4 acc1 = {bb1.x, bb1.y, bb1.z, bb1.w}; \
        acc1 = __builtin_amdgcn_mfma_f32_16x16x32_f16(wb0, h_lo, acc1, 0, 0, 0); \
        acc1 = __builtin_amdgcn_mfma_f32_16x16x32_f16(wb1, h_hi, acc1, 0, 0, 0); \
        float p0 = 0.f, p1 = 0.f, p2 = 0.f; \
        _Pragma("unroll") \
        for (int r = 0; r < 4; ++r) { \
            half2_t rp = pk(acc0[r], acc1[r]); \
            p0 = fdot2(rp, t2[r][0], p0); \
            p1 = fdot2(rp, t2[r][1], p1); \
            p2 = fdot2(rp, t2[r][2], p2); \
        } \
        p0 += __shfl_xor(p0, 16); p0 += __shfl_xor(p0, 32); \
        p1 += __shfl_xor(p1, 16); p1 += __shfl_xor(p1, 32); \
        p2 += __shfl_xor(p2, 16); p2 += __shfl_xor(p2, 32); \
        OUT; \
    }

#define STAGE_W2(group) { \
    uint4* d4 = (uint4*)w2s; \
    _Pragma("unroll") \
    for (int i = 0; i < 8; ++i) d4[i*256 + tid] = w2p[(group)*2048 + i*256 + tid]; \
}

// ---- fused per-edge kernel: session-proven optimum (R9: 53.9 us).
// 256-thread blocks, 3-pass W2 LDS staging (32 KB/pass), MFMA Phase A,
// (256,3) bound -> VGPR 68, no spill, ~2 blocks/CU.
__global__ __launch_bounds__(256, 3)
void fused_kernel(const int* __restrict__ src, const int* __restrict__ dst,
                  const float* __restrict__ basis, const float* __restrict__ efeat,
                  const float* __restrict__ f,
                  const uint4* __restrict__ w1pk, const float* __restrict__ b1,
                  const uint4* __restrict__ w2p, const float* __restrict__ b2,
                  unsigned char* __restrict__ bkt, int* __restrict__ cnt,
                  float* __restrict__ num, float* __restrict__ den)
{
    __shared__ __fp16 w2s[8*4*64*8];    // 32 KB, one 8-c-row group
    __shared__ float  b2s[768];         // 3 KB

    const int tid  = threadIdx.x;
    const int lane = tid & 63;
    const int wid  = tid >> 6;
    const int em   = lane & 15;
    const int quad = lane >> 4;
    const int e = (blockIdx.x * 4 + wid) * 16 + em;

    // ---- W1 A-fragments + bias (tiny, L2-resident; issue early) ----
    half8_t w1f[4];
    {
        #pragma unroll
        for (int t = 0; t < 4; ++t) {
            union { uint4 u; half8_t v; } c;
            c.u = w1pk[(t << 6) + lane];
            w1f[t] = c.v;
        }
    }
    float4 b1a = *(const float4*)(b1 + quad*8);
    float4 b1b = *(const float4*)(b1 + quad*8 + 4);
    float4 b1c = *(const float4*)(b1 + 32 + quad*8);
    float4 b1d = *(const float4*)(b1 + 32 + quad*8 + 4);

    // ---- x B-fragment: this quad's 8 features of edge e ----
    half8_t xb;
    {
        const float4* xv = (const float4*)(efeat + (size_t)e * 32 + quad*8);
        float4 x0 = xv[0], x1 = xv[1];
        union { half2_t h2[4]; half8_t v; } xu;
        xu.h2[0] = pk(x0.x, x0.y); xu.h2[1] = pk(x0.z, x0.w);
        xu.h2[2] = pk(x1.x, x1.y); xu.h2[3] = pk(x1.z, x1.w);
        xb = xu.v;
    }

    // ---- stage pass-1 (k rows c=0..7) + b2 ----
    STAGE_W2(0);
    if (tid < 192) ((float4*)b2s)[tid] = ((const float4*)b2)[tid];

    // ---- bucket placement: one atomic per edge, slot broadcast to all quads ----
    int p_slot = 0, dn0 = 0;
    if (quad == 0) {
        dn0 = dst[e];
        p_slot = atomicAdd(&cnt[dn0], 1);
    }
    const int pb  = __shfl(p_slot, em);
    const int dnb = __shfl(dn0, em);

    // ---- Phase A via MFMA: h = relu(W1 @ x + b1), C-init = bias ----
    half8_t h_lo, h_hi;
    {
        f32x4 ha0 = {b1a.x, b1a.y, b1a.z, b1a.w};
        f32x4 ha1 = {b1b.x, b1b.y, b1b.z, b1b.w};
        f32x4 ha2 = {b1c.x, b1c.y, b1c.z, b1c.w};
        f32x4 ha3 = {b1d.x, b1d.y, b1d.z, b1d.w};
        ha0 = __builtin_amdgcn_mfma_f32_16x16x32_f16(w1f[0], xb, ha0, 0, 0, 0);
        ha1 = __builtin_amdgcn_mfma_f32_16x16x32_f16(w1f[1], xb, ha1, 0, 0, 0);
        ha2 = __builtin_amdgcn_mfma_f32_16x16x32_f16(w1f[2], xb, ha2, 0, 0, 0);
        ha3 = __builtin_amdgcn_mfma_f32_16x16x32_f16(w1f[3], xb, ha3, 0, 0, 0);
        union { half2_t h2[4]; half8_t v; } lo, hi;
        lo.h2[0] = pk(fmaxf(ha0[0],0.f), fmaxf(ha0[1],0.f));
        lo.h2[1] = pk(fmaxf(ha0[2],0.f), fmaxf(ha0[3],0.f));
        lo.h2[2] = pk(fmaxf(ha1[0],0.f), fmaxf(ha1[1],0.f));
        lo.h2[3] = pk(fmaxf(ha1[2],0.f), fmaxf(ha1[3],0.f));
        hi.h2[0] = pk(fmaxf(ha2[0],0.f), fmaxf(ha2[1],0.f));
        hi.h2[1] = pk(fmaxf(ha2[2],0.f), fmaxf(ha2[3],0.f));
        hi.h2[2] = pk(fmaxf(ha3[0],0.f), fmaxf(ha3[1],0.f));
        hi.h2[3] = pk(fmaxf(ha3[2],0.f), fmaxf(ha3[3],0.f));
        h_lo = lo.v; h_hi = hi.v;
    }

    // ---- Phase B: tmp2 quarter (mp = quad*4..+4), pairs (m', m'+16) ----
    half2_t t2[4][3];
    {
        float bas[18];
        const float2* bv = (const float2*)(basis + (size_t)e * 18);
        #pragma unroll
        for (int i = 0; i < 9; ++i) { float2 t = bv[i]; bas[2*i] = t.x; bas[2*i+1] = t.y; }
        const float* fp = f + (size_t)src[e] * 48 + quad*6;
        float fl[6], fh[6];
        #pragma unroll
        for (int i = 0; i < 3; ++i) {
            float2 a = *(const float2*)(fp + 2*i);      fl[2*i] = a.x; fl[2*i+1] = a.y;
            float2 b = *(const float2*)(fp + 24 + 2*i); fh[2*i] = b.x; fh[2*i+1] = b.y;
        }
        #pragma unroll
        for (int jj = 0; jj < 4; ++jj) {
            const int mr = (jj >> 1) * 3;
            const int rb = (jj & 1) * 3;
            #pragma unroll
            for (int d = 0; d < 3; ++d) {
                float lo = fmaf(fl[mr+0], bas[rb+d],
                           fmaf(fl[mr+1], bas[6+rb+d], fl[mr+2] * bas[12+rb+d]));
                float hi = fmaf(fh[mr+0], bas[rb+d],
                           fmaf(fh[mr+1], bas[6+rb+d], fh[mr+2] * bas[12+rb+d]));
                t2[jj][d] = pk(lo, hi);
            }
        }
    }

    __syncthreads();

    // ---- pass 1: k rows (c = 0..7) ----
    float kreg[8][3];
    CONV_GROUP(0, { kreg[cg][0]=p0; kreg[cg][1]=p1; kreg[cg][2]=p2; });

    // ---- pass 2: q rows (c = 8..15) -> scores ----
    __syncthreads();
    STAGE_W2(1);
    __syncthreads();
    float sreg[4];
    CONV_GROUP(8, {
        float s_ = p0*kreg[cg][0] + p1*kreg[cg][1] + p2*kreg[cg][2];
        if ((cg & 1) == 0) sreg[cg>>1] = s_; else sreg[cg>>1] += s_;
    });

    // exp(leaky_relu(s*temp)) on all lanes; no max subtraction (verified R2-R14).
    float exv[4];
    #pragma unroll
    for (int hh = 0; hh < 4; ++hh) {
        float s = sreg[hh] * TEMP;
        s = (s > 0.0f) ? s : 0.2f * s;
        exv[hh] = __expf(s);
    }

    // ---- pass 3: v rows (c = 16..23) ----
    __syncthreads();
    STAGE_W2(2);
    __syncthreads();
    float vreg[8][3];
    CONV_GROUP(16, { vreg[cg][0]=p0; vreg[cg][1]=p1; vreg[cg][2]=p2; });

    // ---- epilogue: 64 B bucket record, four plain 16 B stores ----
    if (pb < SLOTS) {
        unsigned char* rec = bkt + ((size_t)dnb * SLOTS + pb) * 64;
        if (quad == 3) {
            *(float4*)(rec + 48) = make_float4(exv[0], exv[1], exv[2], exv[3]);
        } else {
            union { half2_t h2[4]; uint4 u; } pv;
            if (quad == 0) {
                pv.h2[0] = pk(vreg[0][0], vreg[0][1]);
                pv.h2[1] = pk(vreg[0][2], vreg[1][0]);
                pv.h2[2] = pk(vreg[1][1], vreg[1][2]);
                pv.h2[3] = pk(vreg[2][0], vreg[2][1]);
            } else if (quad == 1) {
                pv.h2[0] = pk(vreg[2][2], vreg[3][0]);
                pv.h2[1] = pk(vreg[3][1], vreg[3][2]);
                pv.h2[2] = pk(vreg[4][0], vreg[4][1]);
                pv.h2[3] = pk(vreg[4][2], vreg[5][0]);
            } else {
                pv.h2[0] = pk(vreg[5][1], vreg[5][2]);
                pv.h2[1] = pk(vreg[6][0], vreg[6][1]);
                pv.h2[2] = pk(vreg[6][2], vreg[7][0]);
                pv.h2[3] = pk(vreg[7][1], vreg[7][2]);
            }
            *(uint4*)(rec + quad*16) = pv.u;
        }
    } else {
        // rare overflow: atomic fallback
        float* nb = num + (size_t)dnb * 24;
        if (quad == 0) {
            atomicAdd(nb+0, exv[0]*vreg[0][0]); atomicAdd(nb+1, exv[0]*vreg[0][1]);
            atomicAdd(nb+2, exv[0]*vreg[0][2]); atomicAdd(nb+3, exv[0]*vreg[1][0]);
            atomicAdd(nb+4, exv[0]*vreg[1][1]); atomicAdd(nb+5, exv[0]*vreg[1][2]);
            atomicAdd(nb+6, exv[1]*vreg[2][0]); atomicAdd(nb+7, exv[1]*vreg[2][1]);
        } else if (quad == 1) {
            atomicAdd(nb+8,  exv[1]*vreg[2][2]); atomicAdd(nb+9,  exv[1]*vreg[3][0]);
            atomicAdd(nb+10, exv[1]*vreg[3][1]); atomicAdd(nb+11, exv[1]*vreg[3][2]);
            atomicAdd(nb+12, exv[2]*vreg[4][0]); atomicAdd(nb+13, exv[2]*vreg[4][1]);
            atomicAdd(nb+14, exv[2]*vreg[4][2]); atomicAdd(nb+15, exv[2]*vreg[5][0]);
        } else if (quad == 2) {
            atomicAdd(nb+16, exv[2]*vreg[5][1]); atomicAdd(nb+17, exv[2]*vreg[5][2]);
            atomicAdd(nb+18, exv[3]*vreg[6][0]); atomicAdd(nb+19, exv[3]*vreg[6][1]);
            atomicAdd(nb+20, exv[3]*vreg[6][2]); atomicAdd(nb+21, exv[3]*vreg[7][0]);
            atomicAdd(nb+22, exv[3]*vreg[7][1]); atomicAdd(nb+23, exv[3]*vreg[7][2]);
        } else {
            float* db = den + (size_t)dnb * 4;
            atomicAdd(db+0, exv[0]); atomicAdd(db+1, exv[1]);
            atomicAdd(db+2, exv[2]); atomicAdd(db+3, exv[3]);
        }
    }
}

// ---- gather: one wave per node; contiguous 64 B records, no max phase ----
__global__ __launch_bounds__(256)
void gather_kernel(const int* __restrict__ cnt, const unsigned char* __restrict__ bkt,
                   const float* __restrict__ num, const float* __restrict__ den,
                   float* __restrict__ out)
{
    const int lane = threadIdx.x & 63;
    const int wid  = threadIdx.x >> 6;
    const int n = blockIdx.x * 4 + wid;
    if (n >= N_NODES) return;
    int deg = cnt[n];
    if (deg > SLOTS) deg = SLOTS;
    const unsigned char* rec = bkt + (size_t)n * SLOTS * 64;

    const int j = lane & 31;            // output component (j < 24)
    const int half = lane >> 5;         // slot-range split
    const int hd = (j < 24) ? (j / 6) : 0;

    float acc = 0.f, dn_ = 0.f;
    if (j < 24 && half == 0) {          // merge rare overflow contributions
        acc = num[n*24 + j];
        dn_ = den[n*4 + hd];
    }
    if (j < 24) {
        #pragma unroll 2
        for (int i = half; i < deg; i += 2) {
            const unsigned char* r = rec + (size_t)i * 64;
            float ex = *(const float*)(r + 48 + hd*4);
            float v  = (float)*(const __fp16*)(r + j*2);
            dn_ += ex;
            acc = fmaf(ex, v, acc);
        }
    }
    acc += __shfl_xor(acc, 32);
    dn_ += __shfl_xor(dn_, 32);
    if (half == 0 && j < 24) {
        out[n*24 + j] = (dn_ > 0.f) ? (acc / dn_) : 0.f;
    }
}

extern "C" void kernel_launch(void* const* d_in, const int* in_sizes, int n_in,
                              void* d_out, int out_size, void* d_ws, size_t ws_size,
                              hipStream_t stream)
{
    const int*   src   = (const int*)d_in[0];
    const int*   dst   = (const int*)d_in[1];
    const float* basis = (const float*)d_in[2];
    const float* ef    = (const float*)d_in[3];
    const float* f     = (const float*)d_in[4];
    const float* W1    = (const float*)d_in[5];
    const float* b1    = (const float*)d_in[6];
    const float* W2    = (const float*)d_in[7];
    const float* b2    = (const float*)d_in[8];
    float* out = (float*)d_out;

    // workspace (~21.75 MB total; proven budget)
    unsigned char* bkt = (unsigned char*)d_ws;                      // N*SLOTS*64 B (20.48 MB)
    float* num = (float*)(bkt + (size_t)N_NODES * SLOTS * 64);      // N*24 f32 (0.96 MB)
    float* den = num + (size_t)N_NODES * 24;                        // N*4 f32 (0.16 MB)
    unsigned* w2p = (unsigned*)(den + (size_t)N_NODES * 4);         // 24576 u32 (96 KB)
    int* cnt = (int*)(w2p + 24576);                                 // N int (40 KB)
    uint4* w1pk = (uint4*)(cnt + N_NODES);                          // 256 uint4 (4 KB)

    prep_kernel<<<96, 256, 0, stream>>>(W2, W1, w2p, w1pk, cnt, (float4*)num);

    fused_kernel<<<E_EDGES / 64, 256, 0, stream>>>(src, dst, basis, ef, f,
                                                   w1pk, b1, (const uint4*)w2p, b2,
                                                   bkt, cnt, num, den);

    gather_kernel<<<(N_NODES + 3) / 4, 256, 0, stream>>>(cnt, bkt, num, den, out);
}